// Round 1
// baseline (49034.341 us; speedup 1.0000x reference)
//
#include <hip/hip_runtime.h>
#include <hip/hip_cooperative_groups.h>

namespace cg = cooperative_groups;

#define BB 128
#define TT 512
#define DD 256
#define HH 512

__device__ __forceinline__ float sig_(float x) { return 1.0f / (1.0f + __expf(-x)); }

#define FMA4(ACC, AV, WV)                     \
  do {                                        \
    ACC[0] = fmaf((AV), (WV).x, ACC[0]);      \
    ACC[1] = fmaf((AV), (WV).y, ACC[1]);      \
    ACC[2] = fmaf((AV), (WV).z, ACC[2]);      \
    ACC[3] = fmaf((AV), (WV).w, ACC[3]);      \
  } while (0)

// ---------------- projection GEMM: xp = x @ proj_w.T + proj_b ----------------
// M=65536, N=256, K=256. Tile [64x64], Kt=64, thread 4x4.
__global__ __launch_bounds__(256) void proj_kernel(const float* __restrict__ x,
                                                   const float* __restrict__ pw,
                                                   const float* __restrict__ pb,
                                                   float* __restrict__ xp) {
  __shared__ float At[64 * 68];  // [row][k], pitch 68
  __shared__ float Bt[64 * 68];  // [k][n],   pitch 68
  const int bm = blockIdx.x >> 2;
  const int bn = blockIdx.x & 3;
  const int tid = threadIdx.x;
  const int rg = tid >> 4;    // 0..15 -> 4 rows each
  const int cgi = tid & 15;   // 0..15 -> 4 cols each
  const int m0 = bm * 64, n0 = bn * 64;
  float acc[4][4] = {};
  for (int kt = 0; kt < 4; ++kt) {
    const int k0 = kt * 64;
    {  // stage A (row-major, rows are k-contiguous in global)
      const int r = tid >> 2, q = tid & 3;
      const float4* src = (const float4*)(x + (size_t)(m0 + r) * DD + k0 + q * 16);
      float4* dst = (float4*)&At[r * 68 + q * 16];
#pragma unroll
      for (int j = 0; j < 4; ++j) dst[j] = src[j];
    }
    {  // stage B transposed: Bt[k][n]
      const int n = tid & 63, kg = tid >> 6;
      const float4* src = (const float4*)(pw + (size_t)(n0 + n) * DD + k0 + kg * 16);
#pragma unroll
      for (int j = 0; j < 4; ++j) {
        float4 v = src[j];
        const int kk = kg * 16 + j * 4;
        Bt[(kk + 0) * 68 + n] = v.x;
        Bt[(kk + 1) * 68 + n] = v.y;
        Bt[(kk + 2) * 68 + n] = v.z;
        Bt[(kk + 3) * 68 + n] = v.w;
      }
    }
    __syncthreads();
#pragma unroll
    for (int k4 = 0; k4 < 64; k4 += 4) {
      float4 a[4], b[4];
#pragma unroll
      for (int j = 0; j < 4; ++j) a[j] = *(const float4*)&At[(rg * 4 + j) * 68 + k4];
#pragma unroll
      for (int j = 0; j < 4; ++j) b[j] = *(const float4*)&Bt[(k4 + j) * 68 + cgi * 4];
#pragma unroll
      for (int jr = 0; jr < 4; ++jr) {
        FMA4(acc[jr], a[jr].x, b[0]);
        FMA4(acc[jr], a[jr].y, b[1]);
        FMA4(acc[jr], a[jr].z, b[2]);
        FMA4(acc[jr], a[jr].w, b[3]);
      }
    }
    __syncthreads();
  }
  const float4 bias = *(const float4*)&pb[n0 + cgi * 4];
#pragma unroll
  for (int jr = 0; jr < 4; ++jr) {
    float4 o;
    o.x = acc[jr][0] + bias.x;
    o.y = acc[jr][1] + bias.y;
    o.z = acc[jr][2] + bias.z;
    o.w = acc[jr][3] + bias.w;
    *(float4*)&xp[(size_t)(m0 + rg * 4 + jr) * DD + n0 + cgi * 4] = o;
  }
}

// ---------------- persistent pipelined 2-layer LSTM ----------------
// 256 blocks x 128 threads, cooperative. Phase p: blocks 0..127 do layer0
// step p; blocks 128..255 do layer1 step p-1. One grid.sync per phase.
// Block tile: [64 rows x 8 cells x 4 gates], K staged in 64-wide LDS tiles.
// Thread: 4 rows x 1 cell x 4 gates (16 acc), c-state in 4 registers.

#define AP 76  // A pitch; row r stored at col offset 4*((r>>2)&3) -> 2-way (free) b128 reads
#define AIDX(r, k) ((r) * AP + (k) + ((((r) >> 2) & 3) << 2))

__global__ __launch_bounds__(128) void lstm_kernel(
    const float* __restrict__ xp,
    const float* __restrict__ wx0, const float* __restrict__ bx0,
    const float* __restrict__ wh0, const float* __restrict__ bh0,
    const float* __restrict__ wx1, const float* __restrict__ bx1,
    const float* __restrict__ wh1, const float* __restrict__ bh1,
    float* __restrict__ h0buf, float* __restrict__ h1buf) {
  cg::grid_group grid = cg::this_grid();
  __shared__ float At[64 * AP];  // [row][k] swizzled
  __shared__ float Wt[64 * 36];  // [k][cell*4+gate]
  const int bidx = blockIdx.x;
  const int role = bidx >> 7;  // 0: layer0, 1: layer1
  const int lid = bidx & 127;
  const int bi = lid >> 6;     // row tile (2 x 64 rows)
  const int bj = lid & 63;     // cell tile (64 x 8 cells)
  const int tid = threadIdx.x;
  const int cell = tid & 7;
  const int rowg = tid >> 3;   // 0..15 -> rows rowg*4..+3
  const int m0 = bi * 64;
  const int cell_g = bj * 8 + cell;

  // zero initial h state (ws is re-poisoned before every launch)
  for (int idx = bidx * 128 + tid; idx < 2 * BB * HH; idx += 256 * 128) {
    h0buf[idx] = 0.0f;
    h1buf[idx] = 0.0f;
  }
  __threadfence();
  grid.sync();

  const float* wx = role ? wx1 : wx0;
  const float* wh = role ? wh1 : wh0;
  const float* bx = role ? bx1 : bx0;
  const float* bh = role ? bh1 : bh0;
  const int KX = role ? HH : DD;         // K of the "x" operand
  const int ntiles = (KX + HH) >> 6;     // 12 (L0) or 16 (L1)

  float bg[4];
#pragma unroll
  for (int g = 0; g < 4; ++g) bg[g] = bx[g * HH + cell_g] + bh[g * HH + cell_g];

  float cst[4] = {0.f, 0.f, 0.f, 0.f};

  for (int p = 0; p <= TT; ++p) {
    const bool active = role ? (p >= 1) : (p < TT);
    if (active) {
      const int t = role ? (p - 1) : p;
      const int rdbuf = (p + 1) & 1;  // written during phase p-1 (or zero-init)
      const int wrbuf = p & 1;
      const float* hprev = (role ? h1buf : h0buf) + (size_t)rdbuf * BB * HH;
      const float* xsrc;
      size_t xstride;
      if (role) { xsrc = h0buf + (size_t)rdbuf * BB * HH; xstride = HH; }
      else      { xsrc = xp + (size_t)t * DD;             xstride = (size_t)TT * DD; }
      float acc[4][4] = {};
      for (int kt = 0; kt < ntiles; ++kt) {
        const int kx = kt << 6;
        {  // ---- stage A: 64 rows x 64 k ----
          const int r = tid >> 1, hf = tid & 1;
          const float* s;
          if (kx < KX) s = xsrc + (size_t)(m0 + r) * xstride + kx + hf * 32;
          else         s = hprev + (size_t)(m0 + r) * HH + (kx - KX) + hf * 32;
          float4* dst = (float4*)&At[AIDX(r, hf * 32)];
#pragma unroll
          for (int j = 0; j < 8; ++j) dst[j] = ((const float4*)s)[j];
        }
        {  // ---- stage W transposed: Wt[k][cell*4+gate] ----
          const int n = tid & 31, kg = tid >> 5;
          const int lc = n >> 2, g = n & 3;
          const int grow = g * HH + bj * 8 + lc;  // global gate row 0..2047
          const float* s;
          if (kx < KX) s = wx + (size_t)grow * KX + kx + kg * 16;
          else         s = wh + (size_t)grow * HH + (kx - KX) + kg * 16;
#pragma unroll
          for (int j = 0; j < 4; ++j) {
            float4 v = ((const float4*)s)[j];
            const int kk = kg * 16 + j * 4;
            Wt[(kk + 0) * 36 + n] = v.x;
            Wt[(kk + 1) * 36 + n] = v.y;
            Wt[(kk + 2) * 36 + n] = v.z;
            Wt[(kk + 3) * 36 + n] = v.w;
          }
        }
        __syncthreads();
#pragma unroll
        for (int k4 = 0; k4 < 64; k4 += 4) {
          float4 a[4], w[4];
#pragma unroll
          for (int j = 0; j < 4; ++j) a[j] = *(const float4*)&At[AIDX(rowg * 4 + j, k4)];
#pragma unroll
          for (int j = 0; j < 4; ++j) w[j] = *(const float4*)&Wt[(k4 + j) * 36 + cell * 4];
#pragma unroll
          for (int jr = 0; jr < 4; ++jr) {
            FMA4(acc[jr], a[jr].x, w[0]);
            FMA4(acc[jr], a[jr].y, w[1]);
            FMA4(acc[jr], a[jr].z, w[2]);
            FMA4(acc[jr], a[jr].w, w[3]);
          }
        }
        __syncthreads();
      }
      // ---- cell update + h store ----
      float* hout = (role ? h1buf : h0buf) + (size_t)wrbuf * BB * HH;
#pragma unroll
      for (int jr = 0; jr < 4; ++jr) {
        const float iv = acc[jr][0] + bg[0];
        const float fv = acc[jr][1] + bg[1];
        const float gv = acc[jr][2] + bg[2];
        const float ov = acc[jr][3] + bg[3];
        const float cn = sig_(fv) * cst[jr] + sig_(iv) * tanhf(gv);
        cst[jr] = cn;
        hout[(size_t)(m0 + rowg * 4 + jr) * HH + cell_g] = sig_(ov) * tanhf(cn);
      }
    }
    __threadfence();
    grid.sync();
  }
}

// ---------------- head: out = relu(h1 @ fc1.T + b1) @ fc2.T + b2 ----------------
__global__ __launch_bounds__(256) void head_kernel(const float* __restrict__ h1,
                                                   const float* __restrict__ fc1w,
                                                   const float* __restrict__ fc1b,
                                                   const float* __restrict__ fc2w,
                                                   const float* __restrict__ fc2b,
                                                   float* __restrict__ out) {
  __shared__ float part[256];
  __shared__ float hid[32];
  const int r = blockIdx.x;
  const int tid = threadIdx.x;
  const int c = tid & 31, pt = tid >> 5;  // 32 cols x 8 K-parts
  const float4* ha = (const float4*)(h1 + (size_t)r * HH + pt * 64);
  const float4* wa = (const float4*)(fc1w + (size_t)c * HH + pt * 64);
  float s = 0.f;
#pragma unroll
  for (int j = 0; j < 16; ++j) {
    float4 av = ha[j], wv = wa[j];
    s = fmaf(av.x, wv.x, s);
    s = fmaf(av.y, wv.y, s);
    s = fmaf(av.z, wv.z, s);
    s = fmaf(av.w, wv.w, s);
  }
  part[tid] = s;
  __syncthreads();
  if (tid < 32) {
    float v = fc1b[tid];
#pragma unroll
    for (int q = 0; q < 8; ++q) v += part[q * 32 + tid];
    hid[tid] = fmaxf(v, 0.f);
  }
  __syncthreads();
  if (tid == 0) {
    float v = fc2b[0];
    for (int cc = 0; cc < 32; ++cc) v = fmaf(hid[cc], fc2w[cc], v);
    out[r] = v;
  }
}

extern "C" void kernel_launch(void* const* d_in, const int* in_sizes, int n_in,
                              void* d_out, int out_size, void* d_ws, size_t ws_size,
                              hipStream_t stream) {
  const float* x    = (const float*)d_in[0];
  const float* pw   = (const float*)d_in[1];
  const float* pb   = (const float*)d_in[2];
  const float* wx0  = (const float*)d_in[3];
  const float* bx0  = (const float*)d_in[4];
  const float* wh0  = (const float*)d_in[5];
  const float* bh0  = (const float*)d_in[6];
  const float* wx1  = (const float*)d_in[7];
  const float* bx1  = (const float*)d_in[8];
  const float* wh1  = (const float*)d_in[9];
  const float* bh1  = (const float*)d_in[10];
  const float* fc1w = (const float*)d_in[11];
  const float* fc1b = (const float*)d_in[12];
  const float* fc2w = (const float*)d_in[13];
  const float* fc2b = (const float*)d_in[14];
  float* out = (float*)d_out;

  // workspace layout (floats): xp [B*T*D] | h0buf [2*B*H] | h1buf [2*B*H]
  float* xp = (float*)d_ws;
  float* h0buf = xp + (size_t)BB * TT * DD;
  float* h1buf = h0buf + 2 * BB * HH;

  proj_kernel<<<dim3(4096), dim3(256), 0, stream>>>(x, pw, pb, xp);

  void* kargs[] = {(void*)&xp,  (void*)&wx0, (void*)&bx0, (void*)&wh0,
                   (void*)&bh0, (void*)&wx1, (void*)&bx1, (void*)&wh1,
                   (void*)&bh1, (void*)&h0buf, (void*)&h1buf};
  hipLaunchCooperativeKernel((void*)lstm_kernel, dim3(256), dim3(128), kargs, 0,
                             stream);

  // final h1 lives in buffer index (512 & 1) == 0
  head_kernel<<<dim3(BB), dim3(256), 0, stream>>>(h1buf, fc1w, fc1b, fc2w, fc2b, out);
}